// Round 3
// baseline (757.943 us; speedup 1.0000x reference)
//
#include <hip/hip_runtime.h>
#include <hip/hip_bf16.h>

#define BB 512
#define TT 512
#define HH 100
#define DI 101
#define DOUT 2
#define BT (BB * TT)

typedef float f4 __attribute__((ext_vector_type(4)));

// ---------------------------------------------------------------------------
// Kernel 0 (prep): pack Wx [100][101] into 16B-aligned padded WxP [100][104],
// cols 101..103 = 0. 41.6 KB, one block, ~2 us. Lets k_inproj load W
// fragments as aligned dwordx4 (the 404-byte source rows are never aligned).
// ---------------------------------------------------------------------------
__global__ void k_prep(const float* __restrict__ Wx, float* __restrict__ WxP) {
  const int t = threadIdx.x;
  for (int idx = t; idx < HH * 104; idx += 256) {
    const int r = idx / 104;
    const int c = idx - r * 104;
    WxP[idx] = (c < DI) ? Wx[r * DI + c] : 0.f;
  }
}

// ---------------------------------------------------------------------------
// Kernel 1: xp[r, c] = dot(in[r, :101], Wx[c, :101]) + b[c]
// ROUND-2 CHANGES (memory paths only, compute phase untouched):
//  * staging: was 52 scattered scalar loads/thread (64 lanes spread over
//    32 rows x 404B -> dozens of cache lines per instr). Now: the block's
//    64 rows are one contiguous 25856B chunk (16B-aligned since
//    64*101*4 = 25856 = 1616*16); load 1616 float4 coalesced (13/thread),
//    remap flat index m -> (r=m/101, c=m%101) -> padded LDS [64][104] with
//    4 scalar ds_writes (magic-mul division, pure VALU).
//  * W fragments: from padded WxP -> 26 aligned dwordx4 loads (L1-hit).
// ---------------------------------------------------------------------------
__global__ __launch_bounds__(128, 2) void k_inproj(
    const float* __restrict__ in, const float* __restrict__ WxP,
    const float* __restrict__ bias, float* __restrict__ xp) {
  const int t = threadIdx.x;
  const int p = t >> 1;    // pair id 0..63
  const int kh = t & 1;    // k half
  const int c0 = p;        // always < 100
  const int c1 = p + 64;
  const bool c1ok = (c1 < HH);

  __shared__ __align__(16) float Atile[64 * 104];

  // --- W fragments: aligned float4 from padded WxP (pad cols are 0) ---
  f4 wx0[13], wx1[13];
  {
    const f4* w0p = (const f4*)(WxP + (size_t)c0 * 104 + kh * 52);
    const f4* w1p = (const f4*)(WxP + (size_t)(c1ok ? c1 : 0) * 104 + kh * 52);
#pragma unroll
    for (int j = 0; j < 13; ++j) {
      wx0[j] = w0p[j];
      wx1[j] = w1p[j];
    }
  }
  const float bs0 = bias[c0];
  const float bs1 = c1ok ? bias[c1] : 0.f;

  const int row0 = blockIdx.x * 64;

  // --- coalesced staging: 1616 quads, thread t takes quads j*128+t ---
  {
    const f4* src = (const f4*)(in + (size_t)row0 * DI);  // 16B-aligned
#pragma unroll
    for (int j = 0; j < 13; ++j) {
      const int Q = j * 128 + t;
      if (Q < 1616) {
        f4 v = src[Q];
        const int m = 4 * Q;  // flat dword index = r*101 + c
#pragma unroll
        for (int kcomp = 0; kcomp < 4; ++kcomp) {
          const int mi = m + kcomp;
          const int r = mi / 101;          // magic-mul
          const int c = mi - r * 101;
          Atile[r * 104 + c] = v[kcomp];
        }
      }
    }
    // zero pads (cols 101..103) so odd-half b128 reads see zeros
    if (t < 64) {
      Atile[t * 104 + 101] = 0.f;
      Atile[t * 104 + 102] = 0.f;
      Atile[t * 104 + 103] = 0.f;
    }
  }
  __syncthreads();

  // --- compute: every thread walks all 64 rows, 2 cols each (unchanged) ---
#pragma unroll 2
  for (int r = 0; r < 64; ++r) {
    const f4* a4 = (const f4*)(Atile + r * 104 + kh * 52);
    f4 s0 = {0.f, 0.f, 0.f, 0.f};
    f4 s1 = {0.f, 0.f, 0.f, 0.f};
#pragma unroll
    for (int j = 0; j < 13; ++j) {
      f4 av = a4[j];
      s0 = __builtin_elementwise_fma(av, wx0[j], s0);
      s1 = __builtin_elementwise_fma(av, wx1[j], s1);
    }
    float p0 = (s0.x + s0.y) + (s0.z + s0.w);
    float p1 = (s1.x + s1.y) + (s1.z + s1.w);
    p0 += __shfl_xor(p0, 1, 64);
    p1 += __shfl_xor(p1, 1, 64);
    if (kh == 0) {
      float* xr = xp + (size_t)(row0 + r) * HH;
      xr[c0] = p0 + bs0;
      if (c1ok) xr[c1] = p1 + bs1;
    }
  }
}

// ---------------------------------------------------------------------------
// Kernel 2: barrier-free scan, one wave per batch (round-1 structure).
// ROUND-2 FIX: round 1 shipped this with w0/w1 as plain loads; LLVM decided
// the __restrict__-const weight loads were cheaper to SINK INTO THE LOOP
// than to keep live (VGPR_Count came back 132, not ~250; step ~2140 cy of
// L1/L2 re-reads). Fix: asm volatile("" : "+v"(w)) after the loads — the
// asm is now the sole def of each weight vector, so the loop body cannot
// rematerialize them from memory; they must stay in VGPRs.
// Also: accumulators split into even/odd partials (dep chain 25 -> 13).
// ---------------------------------------------------------------------------
__global__ __launch_bounds__(64, 1) void k_scan(
    const float* __restrict__ noise, const float* __restrict__ Wh,
    const float* __restrict__ ah0, const float* __restrict__ Wy,
    float* __restrict__ out, float* hstore /* aliases xp staging */) {
  const int b = blockIdx.x;
  const int l = threadIdx.x;   // 0..63
  const bool act = (l < 50);
  const int s0 = act ? 2 * l : 0;  // clamped state-pair base

  __shared__ __align__(16) float h_lds[HH];  // 100 floats = 25 float4

  // --- weights: rows s0, s0+1, pinned resident via asm def-point ---
  f4 w0[25], w1[25];
  {
    const f4* r0 = (const f4*)(Wh + (size_t)s0 * HH);
    const f4* r1 = (const f4*)(Wh + (size_t)(s0 + 1) * HH);
#pragma unroll
    for (int j = 0; j < 25; ++j) {
      w0[j] = r0[j];
      w1[j] = r1[j];
    }
#pragma unroll
    for (int j = 0; j < 25; ++j) {
      asm volatile("" : "+v"(w0[j]), "+v"(w1[j]));
    }
  }
  float wy00 = 0.f, wy01 = 0.f, wy10 = 0.f, wy11 = 0.f;
  if (act) {
    float2 wa = *(const float2*)(Wy + s0);        // Wy[0][s0..s0+1]
    float2 wb = *(const float2*)(Wy + HH + s0);   // Wy[1][s0..s0+1]
    wy00 = wa.x; wy01 = wa.y; wy10 = wb.x; wy11 = wb.y;
  }

  float ahx = 0.f, ahy = 0.f;
  if (act) {
    float2 a = *(const float2*)(ah0 + s0);
    ahx = a.x; ahy = a.y;
  }
  // initial h = retanh(ah0), no noise
  {
    float e0 = __expf(-2.f * ahx);
    float e1 = __expf(-2.f * ahy);
    float h0 = (ahx > 0.f) ? (1.f - e0) * __builtin_amdgcn_rcpf(1.f + e0) : 0.f;
    float h1 = (ahy > 0.f) ? (1.f - e1) * __builtin_amdgcn_rcpf(1.f + e1) : 0.f;
    if (act) *(float2*)&h_lds[s0] = make_float2(h0, h1);
  }

  const float* xp_base = hstore;  // in-place staging from k_inproj
  const size_t bbase = (size_t)b * TT * HH;
  float2* out2 = (float2*)out;

  // 4-deep prefetch
  float2 xpA = make_float2(0.f, 0.f), nzA = xpA;
  float2 xpB = xpA, nzB = xpA, xpC = xpA, nzC = xpA, xpD = xpA, nzD = xpA;
  if (act) {
    xpA = *(const float2*)(xp_base + bbase + (size_t)0 * HH + s0);
    nzA = *(const float2*)(noise + bbase + (size_t)0 * HH + s0);
    xpB = *(const float2*)(xp_base + bbase + (size_t)1 * HH + s0);
    nzB = *(const float2*)(noise + bbase + (size_t)1 * HH + s0);
    xpC = *(const float2*)(xp_base + bbase + (size_t)2 * HH + s0);
    nzC = *(const float2*)(noise + bbase + (size_t)2 * HH + s0);
    xpD = *(const float2*)(xp_base + bbase + (size_t)3 * HH + s0);
    nzD = *(const float2*)(noise + bbase + (size_t)3 * HH + s0);
  }

#define STEP(XP, NZ, tc)                                                      \
  {                                                                           \
    const int tpf = (tc) + 4;                                                 \
    float2 nxp = make_float2(0.f, 0.f), nnz = nxp;                            \
    if (act && tpf < TT) {                                                    \
      nxp = *(const float2*)(xp_base + bbase + (size_t)tpf * HH + s0);        \
      nnz = *(const float2*)(noise + bbase + (size_t)tpf * HH + s0);          \
    }                                                                         \
    const f4* h4 = (const f4*)h_lds;                                          \
    f4 a0e = {0.f, 0.f, 0.f, 0.f}, a0o = a0e;                                 \
    f4 a1e = a0e, a1o = a0e;                                                  \
    _Pragma("unroll") for (int j = 0; j < 24; j += 2) {                       \
      f4 hvE = h4[j];     /* uniform-address broadcast read */                \
      f4 hvO = h4[j + 1];                                                     \
      a0e = __builtin_elementwise_fma(w0[j], hvE, a0e);                       \
      a1e = __builtin_elementwise_fma(w1[j], hvE, a1e);                       \
      a0o = __builtin_elementwise_fma(w0[j + 1], hvO, a0o);                   \
      a1o = __builtin_elementwise_fma(w1[j + 1], hvO, a1o);                   \
    }                                                                         \
    {                                                                         \
      f4 hvL = h4[24];                                                        \
      a0e = __builtin_elementwise_fma(w0[24], hvL, a0e);                      \
      a1e = __builtin_elementwise_fma(w1[24], hvL, a1e);                      \
    }                                                                         \
    f4 acc0 = a0e + a0o;                                                      \
    f4 acc1 = a1e + a1o;                                                      \
    float d0 = (acc0.x + acc0.y) + (acc0.z + acc0.w);                         \
    float d1 = (acc1.x + acc1.y) + (acc1.z + acc1.w);                         \
    ahx = fmaf(0.1f, (d0 + XP.x) - ahx, ahx);                                 \
    ahy = fmaf(0.1f, (d1 + XP.y) - ahy, ahy);                                 \
    float e0 = __expf(-2.f * ahx);                                            \
    float e1 = __expf(-2.f * ahy);                                            \
    float h0 = (ahx > 0.f) ? (1.f - e0) * __builtin_amdgcn_rcpf(1.f + e0)     \
                           : 0.f;                                             \
    float h1 = (ahy > 0.f) ? (1.f - e1) * __builtin_amdgcn_rcpf(1.f + e1)     \
                           : 0.f;                                             \
    h0 += NZ.x;                                                               \
    h1 += NZ.y;                                                               \
    /* all h4 reads above precede this write in wave program order */         \
    if (act) {                                                                \
      *(float2*)&h_lds[s0] = make_float2(h0, h1);                             \
      *(float2*)(hstore + bbase + (size_t)(tc)*HH + s0) =                     \
          make_float2(h0, h1);                                                \
    }                                                                         \
    /* fused output projection: partials then full-wave xor tree */           \
    float po0 = act ? fmaf(h0, wy00, h1 * wy01) : 0.f;                        \
    float po1 = act ? fmaf(h0, wy10, h1 * wy11) : 0.f;                        \
    po0 += __shfl_xor(po0, 1, 64);                                            \
    po1 += __shfl_xor(po1, 1, 64);                                            \
    po0 += __shfl_xor(po0, 2, 64);                                            \
    po1 += __shfl_xor(po1, 2, 64);                                            \
    po0 += __shfl_xor(po0, 4, 64);                                            \
    po1 += __shfl_xor(po1, 4, 64);                                            \
    po0 += __shfl_xor(po0, 8, 64);                                            \
    po1 += __shfl_xor(po1, 8, 64);                                            \
    po0 += __shfl_xor(po0, 16, 64);                                           \
    po1 += __shfl_xor(po1, 16, 64);                                           \
    po0 += __shfl_xor(po0, 32, 64);                                           \
    po1 += __shfl_xor(po1, 32, 64);                                           \
    if (l == 0) out2[(size_t)b * TT + (tc)] = make_float2(po0, po1);          \
    XP = nxp;                                                                 \
    NZ = nnz;                                                                 \
  }

#pragma unroll 1
  for (int tc = 0; tc < TT; tc += 4) {
    STEP(xpA, nzA, tc);
    STEP(xpB, nzB, tc + 1);
    STEP(xpC, nzC, tc + 2);
    STEP(xpD, nzD, tc + 3);
  }
#undef STEP
}

// ---------------------------------------------------------------------------
// Launch
// ---------------------------------------------------------------------------
extern "C" void kernel_launch(void* const* d_in, const int* in_sizes, int n_in,
                              void* d_out, int out_size, void* d_ws,
                              size_t ws_size, hipStream_t stream) {
  const float* input = (const float*)d_in[0];  // [B,T,DI]
  const float* noise = (const float*)d_in[1];  // [B,T,H]
  const float* W_x = (const float*)d_in[2];    // [H,DI]
  const float* b_ah = (const float*)d_in[3];   // [H]
  const float* W_h = (const float*)d_in[4];    // [H,H]
  const float* W_y = (const float*)d_in[5];    // [DO,H]
  const float* ah0 = (const float*)d_in[6];    // [H]

  float* out = (float*)d_out;                    // [B,T,DO]
  float* hstore = out + (size_t)BB * TT * DOUT;  // [B,T,H]
  float* WxP = (float*)d_ws;                     // padded Wx [100][104]

  // K0: pack Wx into aligned padded copy (one tiny block).
  k_prep<<<1, 256, 0, stream>>>(W_x, WxP);

  // K1: input projection -> xp staged into hstore region.
  k_inproj<<<BT / 64, 128, 0, stream>>>(input, WxP, b_ah, hstore);

  // K2: barrier-free scan, one wave per batch; writes hstore + out.
  k_scan<<<BB, 64, 0, stream>>>(noise, W_h, ah0, W_y, out, hstore);
}

// Round 5
// 672.577 us; speedup vs baseline: 1.1269x; 1.1269x over previous
//
#include <hip/hip_runtime.h>
#include <hip/hip_bf16.h>

#define BB 512
#define TT 512
#define HH 100
#define DI 101
#define DOUT 2
#define BT (BB * TT)

typedef float f4 __attribute__((ext_vector_type(4)));

// ---------------------------------------------------------------------------
// Kernel 0 (prep): pack Wx [100][101] into 16B-aligned padded WxP [100][104].
// ---------------------------------------------------------------------------
__global__ void k_prep(const float* __restrict__ Wx, float* __restrict__ WxP) {
  const int t = threadIdx.x;
  for (int idx = t; idx < HH * 104; idx += 256) {
    const int r = idx / 104;
    const int c = idx - r * 104;
    WxP[idx] = (c < DI) ? Wx[r * DI + c] : 0.f;
  }
}

// ---------------------------------------------------------------------------
// Kernel 1: xp[r, c] = dot(in[r, :101], Wx[c, :101]) + b[c]
// ROUND-4 FIX: the per-row pair-reduce was 2 DEPENDENT __shfl_xor
// (ds_bpermute, LDS pipe, ~120cy latency each) x 64 rows — that serial
// latency, not staging, is why this kernel sat at ~280us through rounds
// 0-3 (staging rewrite in r2 changed nothing, the tell). Replaced with
// mov_dpp quad_perm lane^1 (VALU pipe, ~4cy, proven in the r1 scan).
// Exotic amdgpu_* attrs reverted to plain launch_bounds (r3 container
// failure suspect).
// ---------------------------------------------------------------------------
__global__ __launch_bounds__(128, 2) void k_inproj(
    const float* __restrict__ in, const float* __restrict__ WxP,
    const float* __restrict__ bias, float* __restrict__ xp) {
  const int t = threadIdx.x;
  const int p = t >> 1;    // pair id 0..63
  const int kh = t & 1;    // k half
  const int c0 = p;        // always < 100
  const int c1 = p + 64;
  const bool c1ok = (c1 < HH);

  __shared__ __align__(16) float Atile[64 * 104];

  // --- W fragments: aligned float4 from padded WxP ---
  f4 wx0[13], wx1[13];
  {
    const f4* w0p = (const f4*)(WxP + (size_t)c0 * 104 + kh * 52);
    const f4* w1p = (const f4*)(WxP + (size_t)(c1ok ? c1 : 0) * 104 + kh * 52);
#pragma unroll
    for (int j = 0; j < 13; ++j) {
      wx0[j] = w0p[j];
      wx1[j] = w1p[j];
    }
#pragma unroll
    for (int j = 0; j < 13; ++j) {
      asm volatile("" : "+v"(wx0[j]), "+v"(wx1[j]));
    }
  }
  const float bs0 = bias[c0];
  const float bs1 = c1ok ? bias[c1] : 0.f;

  const int row0 = blockIdx.x * 64;

  // --- coalesced staging: 1616 quads, thread t takes quads j*128+t ---
  {
    const f4* src = (const f4*)(in + (size_t)row0 * DI);  // 16B-aligned
#pragma unroll
    for (int j = 0; j < 13; ++j) {
      const int Q = j * 128 + t;
      if (Q < 1616) {
        f4 v = src[Q];
        const int m = 4 * Q;  // flat dword index = r*101 + c
#pragma unroll
        for (int kcomp = 0; kcomp < 4; ++kcomp) {
          const int mi = m + kcomp;
          const int r = mi / 101;          // magic-mul
          const int c = mi - r * 101;
          Atile[r * 104 + c] = v[kcomp];
        }
      }
    }
    // zero pads (cols 101..103) so odd-half b128 reads see zeros
    if (t < 64) {
      Atile[t * 104 + 101] = 0.f;
      Atile[t * 104 + 102] = 0.f;
      Atile[t * 104 + 103] = 0.f;
    }
  }
  __syncthreads();

  // --- compute: every thread walks all 64 rows, 2 cols each ---
#pragma unroll 2
  for (int r = 0; r < 64; ++r) {
    const f4* a4 = (const f4*)(Atile + r * 104 + kh * 52);
    f4 s0 = {0.f, 0.f, 0.f, 0.f};
    f4 s1 = {0.f, 0.f, 0.f, 0.f};
#pragma unroll
    for (int j = 0; j < 13; ++j) {
      f4 av = a4[j];
      s0 = __builtin_elementwise_fma(av, wx0[j], s0);
      s1 = __builtin_elementwise_fma(av, wx1[j], s1);
    }
    float p0 = (s0.x + s0.y) + (s0.z + s0.w);
    float p1 = (s1.x + s1.y) + (s1.z + s1.w);
    // pair-reduce on the VALU pipe: quad_perm [1,0,3,2] swaps lane^1
    p0 += __int_as_float(__builtin_amdgcn_mov_dpp(
        __float_as_int(p0), 0xB1, 0xF, 0xF, true));
    p1 += __int_as_float(__builtin_amdgcn_mov_dpp(
        __float_as_int(p1), 0xB1, 0xF, 0xF, true));
    if (kh == 0) {
      float* xr = xp + (size_t)(row0 + r) * HH;
      xr[c0] = p0 + bs0;
      if (c1ok) xr[c1] = p1 + bs1;
    }
  }
}

// ---------------------------------------------------------------------------
// Kernel 2: barrier-free scan, one wave per batch.
// ROUND-4 FIX (the big one): rounds 1-3 all measured ~2140 cy/step with
// VALUBusy ~15% (=~330cy busy) regardless of weight pinning — the weights
// were never the bottleneck. The fused output-projection xor tree was:
// 12 SEQUENTIALLY DEPENDENT __shfl_xor = ds_bpermute ops at ~120cy each
// on a solo wave (1 wave/SIMD, nothing hides latency) ~= 1440 cy/step.
// Fix: delete the tree; output projection moves back to k_outproj
// (memory-bound, fully parallel). The step now has ZERO cross-lane ops.
// Weight pin kept (launch_bounds(64,1) + asm def-points); VGPR_Count is
// the diagnostic: >=230 means resident, ~132 means per-step reloads
// (worth ~+200-400cy/step, fix next round if so).
// ---------------------------------------------------------------------------
__global__ __launch_bounds__(64, 1) void k_scan(
    const float* __restrict__ noise, const float* __restrict__ Wh,
    const float* __restrict__ ah0, float* hstore /* aliases xp staging */) {
  const int b = blockIdx.x;
  const int l = threadIdx.x;   // 0..63
  const bool act = (l < 50);
  const int s0 = act ? 2 * l : 0;  // clamped state-pair base

  __shared__ __align__(16) float h_lds[HH];  // 100 floats = 25 float4

  // --- weights: rows s0, s0+1, pinned via asm def-point ---
  f4 w0[25], w1[25];
  {
    const f4* r0 = (const f4*)(Wh + (size_t)s0 * HH);
    const f4* r1 = (const f4*)(Wh + (size_t)(s0 + 1) * HH);
#pragma unroll
    for (int j = 0; j < 25; ++j) {
      w0[j] = r0[j];
      w1[j] = r1[j];
    }
#pragma unroll
    for (int j = 0; j < 25; ++j) {
      asm volatile("" : "+v"(w0[j]), "+v"(w1[j]));
    }
  }

  float ahx = 0.f, ahy = 0.f;
  if (act) {
    float2 a = *(const float2*)(ah0 + s0);
    ahx = a.x; ahy = a.y;
  }
  // initial h = retanh(ah0), no noise
  {
    float e0 = __expf(-2.f * ahx);
    float e1 = __expf(-2.f * ahy);
    float h0 = (ahx > 0.f) ? (1.f - e0) * __builtin_amdgcn_rcpf(1.f + e0) : 0.f;
    float h1 = (ahy > 0.f) ? (1.f - e1) * __builtin_amdgcn_rcpf(1.f + e1) : 0.f;
    if (act) *(float2*)&h_lds[s0] = make_float2(h0, h1);
  }

  const float* xp_base = hstore;  // in-place staging from k_inproj
  const size_t bbase = (size_t)b * TT * HH;

  // 4-deep prefetch
  float2 xpA = make_float2(0.f, 0.f), nzA = xpA;
  float2 xpB = xpA, nzB = xpA, xpC = xpA, nzC = xpA, xpD = xpA, nzD = xpA;
  if (act) {
    xpA = *(const float2*)(xp_base + bbase + (size_t)0 * HH + s0);
    nzA = *(const float2*)(noise + bbase + (size_t)0 * HH + s0);
    xpB = *(const float2*)(xp_base + bbase + (size_t)1 * HH + s0);
    nzB = *(const float2*)(noise + bbase + (size_t)1 * HH + s0);
    xpC = *(const float2*)(xp_base + bbase + (size_t)2 * HH + s0);
    nzC = *(const float2*)(noise + bbase + (size_t)2 * HH + s0);
    xpD = *(const float2*)(xp_base + bbase + (size_t)3 * HH + s0);
    nzD = *(const float2*)(noise + bbase + (size_t)3 * HH + s0);
  }

#define STEP(XP, NZ, tc)                                                      \
  {                                                                           \
    const int tpf = (tc) + 4;                                                 \
    float2 nxp = make_float2(0.f, 0.f), nnz = nxp;                            \
    if (act && tpf < TT) {                                                    \
      nxp = *(const float2*)(xp_base + bbase + (size_t)tpf * HH + s0);        \
      nnz = *(const float2*)(noise + bbase + (size_t)tpf * HH + s0);          \
    }                                                                         \
    const f4* h4 = (const f4*)h_lds;                                          \
    f4 a0e = {0.f, 0.f, 0.f, 0.f}, a0o = a0e;                                 \
    f4 a1e = a0e, a1o = a0e;                                                  \
    _Pragma("unroll") for (int j = 0; j < 24; j += 2) {                       \
      f4 hvE = h4[j];     /* uniform-address broadcast read */                \
      f4 hvO = h4[j + 1];                                                     \
      a0e = __builtin_elementwise_fma(w0[j], hvE, a0e);                       \
      a1e = __builtin_elementwise_fma(w1[j], hvE, a1e);                       \
      a0o = __builtin_elementwise_fma(w0[j + 1], hvO, a0o);                   \
      a1o = __builtin_elementwise_fma(w1[j + 1], hvO, a1o);                   \
    }                                                                         \
    {                                                                         \
      f4 hvL = h4[24];                                                        \
      a0e = __builtin_elementwise_fma(w0[24], hvL, a0e);                      \
      a1e = __builtin_elementwise_fma(w1[24], hvL, a1e);                      \
    }                                                                         \
    f4 acc0 = a0e + a0o;                                                      \
    f4 acc1 = a1e + a1o;                                                      \
    float d0 = (acc0.x + acc0.y) + (acc0.z + acc0.w);                         \
    float d1 = (acc1.x + acc1.y) + (acc1.z + acc1.w);                         \
    ahx = fmaf(0.1f, (d0 + XP.x) - ahx, ahx);                                 \
    ahy = fmaf(0.1f, (d1 + XP.y) - ahy, ahy);                                 \
    float e0 = __expf(-2.f * ahx);                                            \
    float e1 = __expf(-2.f * ahy);                                            \
    float h0 = (ahx > 0.f) ? (1.f - e0) * __builtin_amdgcn_rcpf(1.f + e0)     \
                           : 0.f;                                             \
    float h1 = (ahy > 0.f) ? (1.f - e1) * __builtin_amdgcn_rcpf(1.f + e1)     \
                           : 0.f;                                             \
    h0 += NZ.x;                                                               \
    h1 += NZ.y;                                                               \
    /* all h4 reads above precede this write in wave program order */         \
    if (act) {                                                                \
      *(float2*)&h_lds[s0] = make_float2(h0, h1);                             \
      *(float2*)(hstore + bbase + (size_t)(tc)*HH + s0) =                     \
          make_float2(h0, h1);                                                \
    }                                                                         \
    XP = nxp;                                                                 \
    NZ = nnz;                                                                 \
  }

#pragma unroll 1
  for (int tc = 0; tc < TT; tc += 4) {
    STEP(xpA, nzA, tc);
    STEP(xpB, nzB, tc + 1);
    STEP(xpC, nzC, tc + 2);
    STEP(xpD, nzD, tc + 3);
  }
#undef STEP
}

// ---------------------------------------------------------------------------
// Kernel 3: out[r, 0:2] = hstore[r, :] @ Wy^T.  Memory-bound stream of
// hstore (105 MB). Thread-per-row, float4 row loads (row base 400 B, 16B
// aligned), Wy broadcast from LDS, float2 coalesced store. (Round-0 code;
// re-separated from the scan — fusing it cost 1440cy/step of bpermute
// latency inside the serial scan, vs ~25-40us standalone here.)
// ---------------------------------------------------------------------------
__global__ __launch_bounds__(256, 2) void k_outproj(
    const float* __restrict__ hstore, const float* __restrict__ Wy,
    float* __restrict__ out) {
  __shared__ __align__(16) float wy_l[2][HH];
  const int t = threadIdx.x;
  if (t < 2 * HH) {
    int r = t / HH;
    int c = t - r * HH;
    wy_l[r][c] = Wy[t];
  }
  __syncthreads();

  const int row = blockIdx.x * 256 + t;
  const float4* h4 = (const float4*)(hstore + (size_t)row * HH);
  const float4* w0 = (const float4*)wy_l[0];
  const float4* w1 = (const float4*)wy_l[1];
  float4 a0 = make_float4(0.f, 0.f, 0.f, 0.f);
  float4 a1 = make_float4(0.f, 0.f, 0.f, 0.f);
#pragma unroll
  for (int j = 0; j < 25; ++j) {
    float4 hv = h4[j];
    float4 x0 = w0[j];
    float4 x1 = w1[j];
    a0.x = fmaf(hv.x, x0.x, a0.x);
    a0.y = fmaf(hv.y, x0.y, a0.y);
    a0.z = fmaf(hv.z, x0.z, a0.z);
    a0.w = fmaf(hv.w, x0.w, a0.w);
    a1.x = fmaf(hv.x, x1.x, a1.x);
    a1.y = fmaf(hv.y, x1.y, a1.y);
    a1.z = fmaf(hv.z, x1.z, a1.z);
    a1.w = fmaf(hv.w, x1.w, a1.w);
  }
  float d0 = (a0.x + a0.y) + (a0.z + a0.w);
  float d1 = (a1.x + a1.y) + (a1.z + a1.w);
  ((float2*)out)[row] = make_float2(d0, d1);
}

// ---------------------------------------------------------------------------
// Launch
// ---------------------------------------------------------------------------
extern "C" void kernel_launch(void* const* d_in, const int* in_sizes, int n_in,
                              void* d_out, int out_size, void* d_ws,
                              size_t ws_size, hipStream_t stream) {
  const float* input = (const float*)d_in[0];  // [B,T,DI]
  const float* noise = (const float*)d_in[1];  // [B,T,H]
  const float* W_x = (const float*)d_in[2];    // [H,DI]
  const float* b_ah = (const float*)d_in[3];   // [H]
  const float* W_h = (const float*)d_in[4];    // [H,H]
  const float* W_y = (const float*)d_in[5];    // [DO,H]
  const float* ah0 = (const float*)d_in[6];    // [H]

  float* out = (float*)d_out;                    // [B,T,DO]
  float* hstore = out + (size_t)BB * TT * DOUT;  // [B,T,H]
  float* WxP = (float*)d_ws;                     // padded Wx [100][104]

  // K0: pack Wx into aligned padded copy (one tiny block).
  k_prep<<<1, 256, 0, stream>>>(W_x, WxP);

  // K1: input projection -> xp staged into hstore region.
  k_inproj<<<BT / 64, 128, 0, stream>>>(input, WxP, b_ah, hstore);

  // K2: barrier-free scan, one wave per batch (no cross-lane ops).
  k_scan<<<BB, 64, 0, stream>>>(noise, W_h, ah0, hstore);

  // K3: output projection from final hstore.
  k_outproj<<<BT / 256, 256, 0, stream>>>(hstore, W_y, out);
}